// Round 3
// baseline (1839.638 us; speedup 1.0000x reference)
//
// Mega-fusion round 3: custom fast grid barrier replaces cg::grid.sync.
// Round-2 post-mortem: mega ran correctly but 1181us at 1.5% VALUBusy ->
// ~1130us idle = 9 x ~125us cg::grid.sync (single-counter: 1024 serialized
// same-line agent atomics). Fix: two-level sense-reversing barrier
// (32 groups x 32 blocks, spread cachelines, s_sleep polls), state in
// __device__ globals (module-zeroed, not in poisoned workspace; monotonic
// generations make it iteration-safe). Also: GEMM1 hoisted before gather
// (bilinearity: proj commutes with edge-sum) -> runs concurrently with edge
// histogram, 9 syncs -> 8. GEMM LDS XOR-swizzle kills the 6.7M bank conflicts.
#include <hip/hip_runtime.h>
#include <hip/hip_fp16.h>

#define N_NODES 10000
#define N_EDGES 100000
#define D 248
#define DP 256      // padded D
#define HDIM 512
#define NNZ 2480
#define LN_EPS 1e-5f
#define PAD_ROWS 128
#define GRID_MAX 1024
#define NTHR 256
#define NGRP 32

typedef __attribute__((ext_vector_type(8))) _Float16 f16x8_t;  // 8 f16 = 4 VGPRs
typedef __attribute__((ext_vector_type(4))) float f32x4_t;     // MFMA accum

__device__ __forceinline__ unsigned short f2h(float f) {
  return __builtin_bit_cast(unsigned short, __float2half(f));
}
__device__ __forceinline__ unsigned packh2(float a, float b) {
  return __builtin_bit_cast(unsigned, __floats2half2_rn(a, b));
}
__device__ __forceinline__ void gload_lds16(const unsigned short* gp,
                                            unsigned short* lds_base) {
  __builtin_amdgcn_global_load_lds(
      (const __attribute__((address_space(1))) void*)gp,
      (__attribute__((address_space(3))) void*)lds_base, 16, 0, 0);
}

// ---------------------------------------------------------------------------
// Custom two-level grid barrier. State in __device__ globals: zeroed at module
// load, NEVER reset -- sense-reversing with monotonic generations, and every
// barrier leaves counters at 0, so consecutive launches/replays stay correct.
// ---------------------------------------------------------------------------
__device__ int g_lcnt[NGRP * 32];  // per-group arrival counters (128B apart)
__device__ int g_lgen[NGRP * 32];  // per-group generations
__device__ int g_gcnt;             // global arrival counter (one per group)
__device__ int g_ggen;             // global generation

__device__ __forceinline__ int aload(int* p) {
  return __hip_atomic_load(p, __ATOMIC_ACQUIRE, __HIP_MEMORY_SCOPE_AGENT);
}
__device__ __forceinline__ void astore(int* p, int v) {
  __hip_atomic_store(p, v, __ATOMIC_RELEASE, __HIP_MEMORY_SCOPE_AGENT);
}
__device__ __forceinline__ int aadd(int* p, int v) {
  return __hip_atomic_fetch_add(p, v, __ATOMIC_ACQ_REL, __HIP_MEMORY_SCOPE_AGENT);
}

__device__ __forceinline__ void grid_barrier() {
  __syncthreads();
  if (threadIdx.x == 0) {
    __threadfence();  // release this block's writes to agent scope
    const int nblk = gridDim.x;
    const int grp = blockIdx.x & (NGRP - 1);
    int* lcnt = &g_lcnt[grp * 32];
    int* lgen = &g_lgen[grp * 32];
    const int gsz = ((nblk - 1 - grp) >> 5) + 1;  // blocks with bid%32==grp
    const int sense = aload(lgen);
    const int v = aadd(lcnt, 1);
    if (v == gsz - 1) {  // last in group -> arrive at global level
      astore(lcnt, 0);
      const int gsen = aload(&g_ggen);
      const int gv = aadd(&g_gcnt, 1);
      if (gv == NGRP - 1) {  // last group -> release everyone
        astore(&g_gcnt, 0);
        astore(&g_ggen, gsen + 1);
      } else {
        while (aload(&g_ggen) == gsen) __builtin_amdgcn_s_sleep(1);
      }
      astore(lgen, sense + 1);
    } else {
      while (aload(lgen) == sense) __builtin_amdgcn_s_sleep(1);
    }
    __threadfence();  // acquire: invalidate caches before next phase's reads
  }
  __syncthreads();
}

struct MegaArgs {
  const float* features; const int* ei;
  const float* W_msg; const float* W1; const float* b1;
  const float* W2; const float* b2;
  const float* gamma; const float* beta;
  const int* Iv; const int* Jv; const int* Kv; const float* Cv;
  float* out;
  unsigned short* featH; unsigned short* WmH; unsigned short* W1H;
  unsigned short* W2H; unsigned short* S2H; unsigned short* SgH;
  unsigned short* aggH; unsigned short* H1H;
  float* H2;
  int* rsK; int2* trip; int* deg; int2* rs2; int* woff; int* esrc;
};

// 16KB shared union: GEMM staging / bracket node-pairs / CSR build / scan.
union SMem {
  struct { unsigned short As[64 * 64]; unsigned short Bs[64 * 64]; } g;  // 16KB
  struct { unsigned sS2[4][DP]; unsigned sF2[4][DP]; } br;               // 8KB
  struct { int cnt[D]; int off[D]; } csr;                                // 2KB
  int sp[256];                                                           // 1KB
};

__device__ __forceinline__ void cast_row_dev(const float* src, unsigned short* dst,
                                             int r, int sr, int sc, int dc) {
  for (int c = threadIdx.x; c < dc; c += NTHR) {
    float v = (r < sr && c < sc) ? src[(size_t)r * sc + c] : 0.f;
    dst[(size_t)r * dc + c] = f2h(v);
  }
}

// ---------------------------------------------------------------------------
// One 64x64 f16 GEMM-NT tile via MFMA 16x16x32_f16 with XOR-swizzled LDS.
// Staging: lane (srow,sg) loads global col (sg^srow)*8 -> linear LDS slot;
// read: f16-col-block c8 of row r lives at ((c8 ^ (r&7))*8). 2-way max.
// EPI: 0 = f16 out; 1 = +bias +silu f16 out; 2 = +bias(n<D) f32; 3 = f32.
// ---------------------------------------------------------------------------
template <int EPI>
__device__ __forceinline__ void gemm_tile(
    const unsigned short* __restrict__ A, const unsigned short* __restrict__ B,
    const float* __restrict__ bias, void* __restrict__ Cout,
    int M, int ncl2, int K, int lda, int ldb, int ldc, int tile,
    unsigned short* As, unsigned short* Bs) {
  const int tid = threadIdx.x;
  const int wave = tid >> 6;
  const int lane = tid & 63;
  const int wm = wave >> 1;
  const int wn = wave & 1;
  const int ml = lane & 15;
  const int q = lane >> 4;
  const int srow = lane >> 3;
  const int sg = lane & 7;
  const int sgs = sg ^ srow;  // pre-swizzled source column block
  const int ncol = 1 << ncl2;
  const int n0 = (tile & (ncol - 1)) << 6;
  const int m0 = (tile >> ncl2) << 6;

  f32x4_t acc[2][2];
#pragma unroll
  for (int i = 0; i < 2; i++)
#pragma unroll
    for (int j = 0; j < 2; j++) acc[i][j] = (f32x4_t)0.f;

  for (int k0 = 0; k0 < K; k0 += 64) {
#pragma unroll
    for (int i = 0; i < 2; i++) {
      int t = wave * 2 + i;
      gload_lds16(A + (size_t)(m0 + t * 8 + srow) * lda + k0 + sgs * 8, As + t * 512);
    }
#pragma unroll
    for (int i = 0; i < 2; i++) {
      int t = wave * 2 + i;
      gload_lds16(B + (size_t)(n0 + t * 8 + srow) * ldb + k0 + sgs * 8, Bs + t * 512);
    }
    __syncthreads();
#pragma unroll
    for (int kk = 0; kk < 2; kk++) {
      f16x8_t a[2], b[2];
#pragma unroll
      for (int im = 0; im < 2; im++) {
        int row = wm * 32 + im * 16 + ml;
        int c8 = (kk * 4 + q) ^ (row & 7);
        a[im] = *(const f16x8_t*)(As + row * 64 + c8 * 8);
      }
#pragma unroll
      for (int jn = 0; jn < 2; jn++) {
        int row = wn * 32 + jn * 16 + ml;
        int c8 = (kk * 4 + q) ^ (row & 7);
        b[jn] = *(const f16x8_t*)(Bs + row * 64 + c8 * 8);
      }
#pragma unroll
      for (int im = 0; im < 2; im++)
#pragma unroll
        for (int jn = 0; jn < 2; jn++)
          acc[im][jn] = __builtin_amdgcn_mfma_f32_16x16x32_f16(
              a[im], b[jn], acc[im][jn], 0, 0, 0);
    }
    __syncthreads();
  }

  // D[m][n]: n = lane&15, m = quad*4 + reg  [C/D layout dtype-independent]
#pragma unroll
  for (int im = 0; im < 2; im++) {
#pragma unroll
    for (int jn = 0; jn < 2; jn++) {
      int gn = n0 + wn * 32 + jn * 16 + ml;
#pragma unroll
      for (int reg = 0; reg < 4; reg++) {
        int gm = m0 + wm * 32 + im * 16 + q * 4 + reg;
        if (gm >= M) continue;
        float v = acc[im][jn][reg];
        if (EPI == 0) {
          ((unsigned short*)Cout)[(size_t)gm * ldc + gn] = f2h(v);
        } else if (EPI == 1) {
          v += bias[gn];
          v = v / (1.f + __expf(-v));
          ((unsigned short*)Cout)[(size_t)gm * ldc + gn] = f2h(v);
        } else if (EPI == 2) {
          v += (gn < D) ? bias[gn] : 0.f;
          ((float*)Cout)[(size_t)gm * ldc + gn] = v;
        } else {
          ((float*)Cout)[(size_t)gm * ldc + gn] = v;
        }
      }
    }
  }
}

// P0 unit layout: 1250 feat-cast | 256 Wm | 512 W1 | 256 W2 | 40 deg-zero | 1 CSR
#define U_FEAT 1250
#define U_WM (U_FEAT + 256)
#define U_W1 (U_WM + 512)
#define U_W2 (U_W1 + 256)
#define U_ZERO (U_W2 + 40)
#define U_TOTAL (U_ZERO + 1)
// P1 unit layout: 391 hist | 628 gemm1 tiles (10000x256 @ 64x64)
#define HIST_U ((N_EDGES + 255) / 256)
#define G1_TILES (157 * 4)
#define U1_TOTAL (HIST_U + G1_TILES)

template <int PH>
__device__ __forceinline__ void run_phase(const MegaArgs& P, SMem& sm) {
  const int tid = threadIdx.x;

  if constexpr (PH == 0) {
    // casts (f32->f16), deg zero, triple CSR by K
    for (int u = blockIdx.x; u < U_TOTAL; u += gridDim.x) {
      if (u < U_FEAT) {
        const int r = u * 8 + (tid >> 5);
        const int c = tid & 31;
        uint4 o = make_uint4(0u, 0u, 0u, 0u);
        if (c < 31) {
          const float* src = P.features + (size_t)r * D + c * 8;
          float4 v0 = *(const float4*)(src);
          float4 v1 = *(const float4*)(src + 4);
          o.x = packh2(v0.x, v0.y);
          o.y = packh2(v0.z, v0.w);
          o.z = packh2(v1.x, v1.y);
          o.w = packh2(v1.z, v1.w);
        }
        *(uint4*)(P.featH + (size_t)r * DP + c * 8) = o;
      } else if (u < U_WM) {
        cast_row_dev(P.W_msg, P.WmH, u - U_FEAT, D, D, DP);
      } else if (u < U_W1) {
        cast_row_dev(P.W1, P.W1H, u - U_WM, HDIM, D, DP);
      } else if (u < U_W2) {
        cast_row_dev(P.W2, P.W2H, u - U_W1, D, HDIM, HDIM);
      } else if (u < U_ZERO) {
        int i = (u - U_W2) * 256 + tid;
        if (i < N_NODES) P.deg[i] = 0;
      } else {
        for (int k = tid; k < D; k += NTHR) sm.csr.cnt[k] = 0;
        __syncthreads();
        for (int t = tid; t < NNZ; t += NTHR) atomicAdd(&sm.csr.cnt[P.Kv[t]], 1);
        __syncthreads();
        if (tid == 0) {
          int run = 0;
          for (int k = 0; k < D; k++) {
            sm.csr.off[k] = run;
            P.rsK[k] = run;
            run += sm.csr.cnt[k];
          }
          P.rsK[D] = run;
        }
        __syncthreads();
        for (int t = tid; t < NNZ; t += NTHR) {
          int pos = atomicAdd(&sm.csr.off[P.Kv[t]], 1);
          P.trip[pos] = make_int2((P.Jv[t] << 16) | P.Iv[t], __float_as_int(P.Cv[t]));
        }
      }
    }
  } else if constexpr (PH == 1) {
    // hist(tgt) CONCURRENT with S2 = featH @ Wm^T (bilinearity hoist)
    for (int u = blockIdx.x; u < U1_TOTAL; u += gridDim.x) {
      if (u < HIST_U) {
        int e = u * 256 + tid;
        if (e < N_EDGES) atomicAdd(&P.deg[P.ei[N_EDGES + e]], 1);
      } else {
        gemm_tile<0>(P.featH, P.WmH, nullptr, P.S2H, N_NODES, 2, DP, DP, DP, DP,
                     u - HIST_U, sm.g.As, sm.g.Bs);
      }
    }
  } else if constexpr (PH == 2) {
    // exclusive scan of deg (block 0 only)
    if (blockIdx.x == 0) {
      const int base = tid * 40;
      int sum = 0;
      for (int i = 0; i < 40; i++) {
        int idx = base + i;
        if (idx < N_NODES) sum += P.deg[idx];
      }
      sm.sp[tid] = sum;
      __syncthreads();
      if (tid == 0) {
        int run = 0;
        for (int i = 0; i < 256; i++) { int tmp = sm.sp[i]; sm.sp[i] = run; run += tmp; }
      }
      __syncthreads();
      int run = sm.sp[tid];
      for (int i = 0; i < 40; i++) {
        int idx = base + i;
        if (idx < N_NODES) {
          int dg = P.deg[idx];
          P.rs2[idx] = make_int2(run, dg);
          P.woff[idx] = run;
          run += dg;
        }
      }
    }
  } else if constexpr (PH == 3) {
    // place edges into CSR
    for (int u = blockIdx.x; u < HIST_U; u += gridDim.x) {
      int e = u * 256 + tid;
      if (e < N_EDGES) {
        int pos = atomicAdd(&P.woff[P.ei[N_EDGES + e]], 1);
        P.esrc[pos] = P.ei[e];
      }
    }
  } else if constexpr (PH == 4) {
    // gather Sg[n] = sum S2[src], half-wave per node
    const int lane = tid & 63;
    const int half = lane >> 5;
    const int c = lane & 31;
    for (int u = blockIdx.x; u < N_NODES / 8; u += gridDim.x) {
      const int n = u * 8 + (tid >> 5);
      const int2 rd = P.rs2[n];
      const int beg = rd.x, dg = rd.y;
      int eid = (c < dg) ? P.esrc[beg + c] : 0;

      __half2 a0 = __floats2half2_rn(0.f, 0.f), a1 = a0, a2 = a0, a3 = a0;
      __half2 b0 = a0, b1 = a0, b2 = a0, b3 = a0;
      const unsigned short* Sc = P.S2H + (size_t)c * 8;
      const int dc = (dg < 32) ? dg : 32;
      int j = 0;
      for (; j + 2 <= dc; j += 2) {
        int s0 = __shfl(eid, half * 32 + j);
        int s1 = __shfl(eid, half * 32 + j + 1);
        uint4 u0 = *(const uint4*)(Sc + (size_t)s0 * DP);
        uint4 u1 = *(const uint4*)(Sc + (size_t)s1 * DP);
        a0 = __hadd2(a0, __builtin_bit_cast(__half2, u0.x));
        a1 = __hadd2(a1, __builtin_bit_cast(__half2, u0.y));
        a2 = __hadd2(a2, __builtin_bit_cast(__half2, u0.z));
        a3 = __hadd2(a3, __builtin_bit_cast(__half2, u0.w));
        b0 = __hadd2(b0, __builtin_bit_cast(__half2, u1.x));
        b1 = __hadd2(b1, __builtin_bit_cast(__half2, u1.y));
        b2 = __hadd2(b2, __builtin_bit_cast(__half2, u1.z));
        b3 = __hadd2(b3, __builtin_bit_cast(__half2, u1.w));
      }
      for (; j < dg; j++) {
        int s = (j < 32) ? __shfl(eid, half * 32 + j) : P.esrc[beg + j];
        uint4 u0 = *(const uint4*)(Sc + (size_t)s * DP);
        a0 = __hadd2(a0, __builtin_bit_cast(__half2, u0.x));
        a1 = __hadd2(a1, __builtin_bit_cast(__half2, u0.y));
        a2 = __hadd2(a2, __builtin_bit_cast(__half2, u0.z));
        a3 = __hadd2(a3, __builtin_bit_cast(__half2, u0.w));
      }
      uint4 o;
      o.x = __builtin_bit_cast(unsigned, __hadd2(a0, b0));
      o.y = __builtin_bit_cast(unsigned, __hadd2(a1, b1));
      o.z = __builtin_bit_cast(unsigned, __hadd2(a2, b2));
      o.w = __builtin_bit_cast(unsigned, __hadd2(a3, b3));
      *(uint4*)(P.SgH + (size_t)n * DP + c * 8) = o;
    }
  } else if constexpr (PH == 5) {
    // agg = bracket(Sg, featH), packed-f16 node pairs (both sources f16 now)
    for (int u = blockIdx.x; u < N_NODES / 8; u += gridDim.x) {
      const int wv = tid >> 6;
      const int lane = tid & 63;
      const int n0 = u * 8 + wv * 2;
      const int n1 = n0 + 1;
      {
        ushort4 s0 = *(const ushort4*)(P.SgH + (size_t)n0 * DP + lane * 4);
        ushort4 s1 = *(const ushort4*)(P.SgH + (size_t)n1 * DP + lane * 4);
        unsigned* d = &sm.br.sS2[wv][lane * 4];
        d[0] = (unsigned)s0.x | ((unsigned)s1.x << 16);
        d[1] = (unsigned)s0.y | ((unsigned)s1.y << 16);
        d[2] = (unsigned)s0.z | ((unsigned)s1.z << 16);
        d[3] = (unsigned)s0.w | ((unsigned)s1.w << 16);
      }
      {
        ushort4 u0 = *(const ushort4*)(P.featH + (size_t)n0 * DP + lane * 4);
        ushort4 u1 = *(const ushort4*)(P.featH + (size_t)n1 * DP + lane * 4);
        unsigned* d = &sm.br.sF2[wv][lane * 4];
        d[0] = (unsigned)u0.x | ((unsigned)u1.x << 16);
        d[1] = (unsigned)u0.y | ((unsigned)u1.y << 16);
        d[2] = (unsigned)u0.z | ((unsigned)u1.z << 16);
        d[3] = (unsigned)u0.w | ((unsigned)u1.w << 16);
      }
      __syncthreads();
      const unsigned* S2 = sm.br.sS2[wv];
      const unsigned* F2 = sm.br.sF2[wv];
#pragma unroll
      for (int kk = 0; kk < 4; kk++) {
        const int k = lane + kk * 64;
        float a0 = 0.f, a1 = 0.f, b0 = 0.f, b1 = 0.f;
        if (k < D) {
          const int tb = P.rsK[k], te = P.rsK[k + 1];
          int t = tb;
          for (; t + 2 <= te; t += 2) {
            int2 t0 = P.trip[t], t1 = P.trip[t + 1];
            __half2 p0 = __hmul2(__builtin_bit_cast(__half2, S2[t0.x & 0xFFFF]),
                                 __builtin_bit_cast(__half2, F2[t0.x >> 16]));
            __half2 p1 = __hmul2(__builtin_bit_cast(__half2, S2[t1.x & 0xFFFF]),
                                 __builtin_bit_cast(__half2, F2[t1.x >> 16]));
            float2 q0 = __half22float2(p0);
            float2 q1 = __half22float2(p1);
            const float c0 = __int_as_float(t0.y), c1 = __int_as_float(t1.y);
            a0 += c0 * q0.x; a1 += c0 * q0.y;
            b0 += c1 * q1.x; b1 += c1 * q1.y;
          }
          if (t < te) {
            int2 t0 = P.trip[t];
            __half2 p0 = __hmul2(__builtin_bit_cast(__half2, S2[t0.x & 0xFFFF]),
                                 __builtin_bit_cast(__half2, F2[t0.x >> 16]));
            float2 q0 = __half22float2(p0);
            const float c0 = __int_as_float(t0.y);
            a0 += c0 * q0.x; a1 += c0 * q0.y;
          }
        }
        P.aggH[(size_t)n0 * DP + k] = f2h(a0 + b0);  // k>=D -> 0 pad
        P.aggH[(size_t)n1 * DP + k] = f2h(a1 + b1);
      }
      __syncthreads();
    }
  } else if constexpr (PH == 6) {
    // H1 = silu(agg @ W1^T + b1), 1256 tiles
    for (int u = blockIdx.x; u < 157 * 8; u += gridDim.x)
      gemm_tile<1>(P.aggH, P.W1H, P.b1, P.H1H, N_NODES, 3, DP, DP, DP, HDIM, u,
                   sm.g.As, sm.g.Bs);
  } else if constexpr (PH == 7) {
    // H2 = H1 @ W2^T + b2 (f32), 628 tiles
    for (int u = blockIdx.x; u < 157 * 4; u += gridDim.x)
      gemm_tile<2>(P.H1H, P.W2H, P.b2, P.H2, N_NODES, 2, HDIM, HDIM, HDIM, DP, u,
                   sm.g.As, sm.g.Bs);
  } else if constexpr (PH == 8) {
    // out = LN(features + H2), wave per node
    for (int u = blockIdx.x; u < N_NODES / 4; u += gridDim.x) {
      const int wv = tid >> 6;
      const int lane = tid & 63;
      const int n = u * 4 + wv;

      float4 x = make_float4(0.f, 0.f, 0.f, 0.f);
      if (lane < 62) {
        float4 f = *(const float4*)(P.features + (size_t)n * D + lane * 4);
        float4 h = *(const float4*)(P.H2 + (size_t)n * DP + lane * 4);
        x = make_float4(f.x + h.x, f.y + h.y, f.z + h.z, f.w + h.w);
      }
      float s = x.x + x.y + x.z + x.w;
#pragma unroll
      for (int o = 32; o > 0; o >>= 1) s += __shfl_xor(s, o);
      const float mu = s * (1.f / (float)D);
      float4 xc = make_float4(x.x - mu, x.y - mu, x.z - mu, x.w - mu);
      float v = 0.f;
      if (lane < 62) v = xc.x * xc.x + xc.y * xc.y + xc.z * xc.z + xc.w * xc.w;
#pragma unroll
      for (int o = 32; o > 0; o >>= 1) v += __shfl_xor(v, o);
      const float rstd = rsqrtf(v * (1.f / (float)D) + LN_EPS);
      if (lane < 62) {
        float4 g = *(const float4*)(P.gamma + lane * 4);
        float4 b = *(const float4*)(P.beta + lane * 4);
        float4 o;
        o.x = xc.x * rstd * g.x + b.x;
        o.y = xc.y * rstd * g.y + b.y;
        o.z = xc.z * rstd * g.z + b.z;
        o.w = xc.w * rstd * g.w + b.w;
        *(float4*)(P.out + (size_t)n * D + lane * 4) = o;
      }
    }
  }
}

__global__ __launch_bounds__(NTHR, 4) void mega_kernel(MegaArgs P) {
  __shared__ SMem sm;
  run_phase<0>(P, sm); grid_barrier();
  run_phase<1>(P, sm); grid_barrier();
  run_phase<2>(P, sm); grid_barrier();
  run_phase<3>(P, sm); grid_barrier();
  run_phase<4>(P, sm); grid_barrier();
  run_phase<5>(P, sm); grid_barrier();
  run_phase<6>(P, sm); grid_barrier();
  run_phase<7>(P, sm); grid_barrier();
  run_phase<8>(P, sm);
}

template <int PH>
__global__ __launch_bounds__(NTHR) void phase_kernel(MegaArgs P) {
  __shared__ SMem sm;
  run_phase<PH>(P, sm);
}

// ---------------------------------------------------------------------------
extern "C" void kernel_launch(void* const* d_in, const int* in_sizes, int n_in,
                              void* d_out, int out_size, void* d_ws, size_t ws_size,
                              hipStream_t stream) {
  char* cur = (char*)d_ws;
  auto alloc = [&](size_t bytes) {
    char* p = cur;
    cur += (bytes + 255) & ~(size_t)255;
    return p;
  };
  const size_t NP = (size_t)N_NODES + PAD_ROWS;

  MegaArgs A;
  A.features = (const float*)d_in[0];
  A.ei       = (const int*)d_in[1];
  A.W_msg    = (const float*)d_in[2];
  A.W1       = (const float*)d_in[3];
  A.b1       = (const float*)d_in[4];
  A.W2       = (const float*)d_in[5];
  A.b2       = (const float*)d_in[6];
  A.gamma    = (const float*)d_in[7];
  A.beta     = (const float*)d_in[8];
  A.Iv       = (const int*)d_in[9];
  A.Jv       = (const int*)d_in[10];
  A.Kv       = (const int*)d_in[11];
  A.Cv       = (const float*)d_in[12];
  A.out      = (float*)d_out;

  A.featH = (unsigned short*)alloc(NP * DP * 2);
  A.WmH   = (unsigned short*)alloc((size_t)DP * DP * 2);
  A.W1H   = (unsigned short*)alloc((size_t)HDIM * DP * 2);
  A.W2H   = (unsigned short*)alloc((size_t)DP * HDIM * 2);
  A.S2H   = (unsigned short*)alloc(NP * DP * 2);
  A.SgH   = (unsigned short*)alloc(NP * DP * 2);
  A.aggH  = (unsigned short*)alloc(NP * DP * 2);
  A.H1H   = (unsigned short*)alloc(NP * HDIM * 2);
  A.H2    = (float*)alloc((size_t)N_NODES * DP * 4);
  A.rsK   = (int*)alloc((D + 1) * 4);
  A.trip  = (int2*)alloc(NNZ * 8);
  A.deg   = (int*)alloc(N_NODES * 4);
  A.rs2   = (int2*)alloc((size_t)N_NODES * 8);
  A.woff  = (int*)alloc(N_NODES * 4);
  A.esrc  = (int*)alloc(N_EDGES * 4);

  // Capture-safe occupancy query (no allocs, no syncs), cached across calls.
  static int s_max_coresident = -1;
  if (s_max_coresident < 0) {
    int dev = 0;
    (void)hipGetDevice(&dev);
    int ncu = 0;
    if (hipDeviceGetAttribute(&ncu, hipDeviceAttributeMultiprocessorCount, dev) !=
            hipSuccess || ncu <= 0)
      ncu = 0;
    int occ = 0;
    if (hipOccupancyMaxActiveBlocksPerMultiprocessor(
            &occ, (const void*)mega_kernel, NTHR, 0) != hipSuccess || occ < 0)
      occ = 0;
    s_max_coresident = occ * ncu;
  }

  bool done = false;
  if (s_max_coresident >= 256) {  // need >=NGRP and real parallelism
    int grid = s_max_coresident < GRID_MAX ? s_max_coresident : GRID_MAX;
    void* kargs[] = {(void*)&A};
    hipError_t e = hipLaunchCooperativeKernel((const void*)mega_kernel,
                                              dim3(grid), dim3(NTHR), kargs, 0,
                                              stream);
    done = (e == hipSuccess);
  }
  if (!done) {
    // Fallback: identical math as 9 ordinary launches.
    dim3 blk(NTHR);
    phase_kernel<0><<<GRID_MAX, blk, 0, stream>>>(A);
    phase_kernel<1><<<GRID_MAX, blk, 0, stream>>>(A);
    phase_kernel<2><<<1, blk, 0, stream>>>(A);
    phase_kernel<3><<<GRID_MAX, blk, 0, stream>>>(A);
    phase_kernel<4><<<GRID_MAX, blk, 0, stream>>>(A);
    phase_kernel<5><<<GRID_MAX, blk, 0, stream>>>(A);
    phase_kernel<6><<<GRID_MAX, blk, 0, stream>>>(A);
    phase_kernel<7><<<GRID_MAX, blk, 0, stream>>>(A);
    phase_kernel<8><<<GRID_MAX, blk, 0, stream>>>(A);
  }
}

// Round 4
// 160.233 us; speedup vs baseline: 11.4810x; 11.4810x over previous
//
// Round 4: back to plain multi-kernel (mega/grid-sync is structurally wrong on
// 8-XCD CDNA4: in-kernel grid barrier >=100us due to L2 wb/inv + poll storms;
// kernel-boundary flush via CP is ~10us). Minimize DISPATCH COUNT instead:
//   memset(deg) -> prep[casts+CSR+slot-place] -> gemm1 -> gather+bracket
//   -> gemm2 -> gemm3 -> LN              (7 dispatches vs round-0's 10)
// Changes vs round-0 baseline (212us):
//  * hist/scan/place (3 kernels, serial 1-block scan) replaced by ONE
//    slot-place kernel: rank=atomicAdd(deg[tgt]); slot CAP=32; overflow list
//    for correctness on any input (practically empty at Poisson(10)).
//  * bilinearity hoist kept (verified round 3): gemm1 projects features first,
//    gather sums projected rows; gather+bracket fused, Sg stays in LDS.
//  * gemm tiles: XOR-swizzled LDS (verified round 3, kills bank conflicts).
#include <hip/hip_runtime.h>
#include <hip/hip_fp16.h>

#define N_NODES 10000
#define N_EDGES 100000
#define D 248
#define DP 256      // padded D
#define HDIM 512
#define NNZ 2480
#define LN_EPS 1e-5f
#define PAD_ROWS 128
#define NTHR 256
#define CAP 32      // edge slots per node

typedef __attribute__((ext_vector_type(8))) _Float16 f16x8_t;  // 8 f16 = 4 VGPRs
typedef __attribute__((ext_vector_type(4))) float f32x4_t;     // MFMA accum

__device__ __forceinline__ unsigned short f2h(float f) {
  return __builtin_bit_cast(unsigned short, __float2half(f));
}
__device__ __forceinline__ unsigned packh2(float a, float b) {
  return __builtin_bit_cast(unsigned, __floats2half2_rn(a, b));
}
__device__ __forceinline__ void gload_lds16(const unsigned short* gp,
                                            unsigned short* lds_base) {
  __builtin_amdgcn_global_load_lds(
      (const __attribute__((address_space(1))) void*)gp,
      (__attribute__((address_space(3))) void*)lds_base, 16, 0, 0);
}

__device__ __forceinline__ void cast_row_dev(const float* src, unsigned short* dst,
                                             int r, int sr, int sc, int dc) {
  for (int c = threadIdx.x; c < dc; c += NTHR) {
    float v = (r < sr && c < sc) ? src[(size_t)r * sc + c] : 0.f;
    dst[(size_t)r * dc + c] = f2h(v);
  }
}

// ---------------------------------------------------------------------------
// prep: feature cast | Wm cast | W1 cast | W2 cast | triple CSR | slot-place.
// All units independent (deg/ovfc pre-zeroed by hipMemsetAsync).
// ---------------------------------------------------------------------------
#define U_FEAT 1250
#define U_WM (U_FEAT + DP)            // 256 rows
#define U_W1 (U_WM + HDIM)            // 512 rows
#define U_W2 (U_W1 + DP)              // 256 rows
#define U_CSR (U_W2 + 1)
#define HIST_U ((N_EDGES + 255) / 256)
#define U_TOTAL (U_CSR + HIST_U)      // 2666 blocks

__global__ __launch_bounds__(NTHR) void prep_kernel(
    const float* __restrict__ features, const float* __restrict__ W_msg,
    const float* __restrict__ W1, const float* __restrict__ W2,
    const int* __restrict__ ei,
    unsigned short* __restrict__ featH, unsigned short* __restrict__ WmH,
    unsigned short* __restrict__ W1H, unsigned short* __restrict__ W2H,
    const int* __restrict__ Iv, const int* __restrict__ Jv,
    const int* __restrict__ Kv, const float* __restrict__ Cv,
    int* __restrict__ rsK, int2* __restrict__ trip,
    int* __restrict__ deg, int* __restrict__ ovfc,
    int* __restrict__ esrc, int2* __restrict__ ovf) {
  const int u = blockIdx.x;
  const int tid = threadIdx.x;
  if (u < U_FEAT) {
    const int r = u * 8 + (tid >> 5);
    const int c = tid & 31;
    uint4 o = make_uint4(0u, 0u, 0u, 0u);
    if (c < 31) {
      const float* src = features + (size_t)r * D + c * 8;
      float4 v0 = *(const float4*)(src);
      float4 v1 = *(const float4*)(src + 4);
      o.x = packh2(v0.x, v0.y);
      o.y = packh2(v0.z, v0.w);
      o.z = packh2(v1.x, v1.y);
      o.w = packh2(v1.z, v1.w);
    }
    *(uint4*)(featH + (size_t)r * DP + c * 8) = o;
  } else if (u < U_WM) {
    cast_row_dev(W_msg, WmH, u - U_FEAT, D, D, DP);
  } else if (u < U_W1) {
    cast_row_dev(W1, W1H, u - U_WM, HDIM, D, DP);
  } else if (u < U_W2) {
    cast_row_dev(W2, W2H, u - U_W1, D, HDIM, HDIM);
  } else if (u < U_CSR) {
    __shared__ int cnt[D];
    __shared__ int off[D];
    for (int k = tid; k < D; k += NTHR) cnt[k] = 0;
    __syncthreads();
    for (int t = tid; t < NNZ; t += NTHR) atomicAdd(&cnt[Kv[t]], 1);
    __syncthreads();
    if (tid == 0) {
      int run = 0;
      for (int k = 0; k < D; k++) { off[k] = run; rsK[k] = run; run += cnt[k]; }
      rsK[D] = run;
    }
    __syncthreads();
    for (int t = tid; t < NNZ; t += NTHR) {
      int pos = atomicAdd(&off[Kv[t]], 1);
      trip[pos] = make_int2((Jv[t] << 16) | Iv[t], __float_as_int(Cv[t]));
    }
  } else {
    // slot-place: rank via atomicAdd; overflow list for rank >= CAP
    int e = (u - U_CSR) * 256 + tid;
    if (e < N_EDGES) {
      int src = ei[e];
      int tgt = ei[N_EDGES + e];
      int r = atomicAdd(&deg[tgt], 1);
      if (r < CAP) {
        esrc[tgt * CAP + r] = src;
      } else {
        int o = atomicAdd(ovfc, 1);
        ovf[o] = make_int2(tgt, src);
      }
    }
  }
}

// ---------------------------------------------------------------------------
// One 64x64 f16 GEMM-NT tile via MFMA 16x16x32_f16 with XOR-swizzled LDS.
// (verified round 3). EPI: 0 f16 out; 1 +bias+silu f16; 2 +bias(n<D) f32.
// ---------------------------------------------------------------------------
template <int EPI>
__device__ __forceinline__ void gemm_tile(
    const unsigned short* __restrict__ A, const unsigned short* __restrict__ B,
    const float* __restrict__ bias, void* __restrict__ Cout,
    int M, int ncl2, int K, int lda, int ldb, int ldc, int tile,
    unsigned short* As, unsigned short* Bs) {
  const int tid = threadIdx.x;
  const int wave = tid >> 6;
  const int lane = tid & 63;
  const int wm = wave >> 1;
  const int wn = wave & 1;
  const int ml = lane & 15;
  const int q = lane >> 4;
  const int srow = lane >> 3;
  const int sg = lane & 7;
  const int sgs = sg ^ srow;  // pre-swizzled source column block
  const int ncol = 1 << ncl2;
  const int n0 = (tile & (ncol - 1)) << 6;
  const int m0 = (tile >> ncl2) << 6;

  f32x4_t acc[2][2];
#pragma unroll
  for (int i = 0; i < 2; i++)
#pragma unroll
    for (int j = 0; j < 2; j++) acc[i][j] = (f32x4_t)0.f;

  for (int k0 = 0; k0 < K; k0 += 64) {
#pragma unroll
    for (int i = 0; i < 2; i++) {
      int t = wave * 2 + i;
      gload_lds16(A + (size_t)(m0 + t * 8 + srow) * lda + k0 + sgs * 8, As + t * 512);
    }
#pragma unroll
    for (int i = 0; i < 2; i++) {
      int t = wave * 2 + i;
      gload_lds16(B + (size_t)(n0 + t * 8 + srow) * ldb + k0 + sgs * 8, Bs + t * 512);
    }
    __syncthreads();
#pragma unroll
    for (int kk = 0; kk < 2; kk++) {
      f16x8_t a[2], b[2];
#pragma unroll
      for (int im = 0; im < 2; im++) {
        int row = wm * 32 + im * 16 + ml;
        int c8 = (kk * 4 + q) ^ (row & 7);
        a[im] = *(const f16x8_t*)(As + row * 64 + c8 * 8);
      }
#pragma unroll
      for (int jn = 0; jn < 2; jn++) {
        int row = wn * 32 + jn * 16 + ml;
        int c8 = (kk * 4 + q) ^ (row & 7);
        b[jn] = *(const f16x8_t*)(Bs + row * 64 + c8 * 8);
      }
#pragma unroll
      for (int im = 0; im < 2; im++)
#pragma unroll
        for (int jn = 0; jn < 2; jn++)
          acc[im][jn] = __builtin_amdgcn_mfma_f32_16x16x32_f16(
              a[im], b[jn], acc[im][jn], 0, 0, 0);
    }
    __syncthreads();
  }

  // D[m][n]: n = lane&15, m = quad*4 + reg
#pragma unroll
  for (int im = 0; im < 2; im++) {
#pragma unroll
    for (int jn = 0; jn < 2; jn++) {
      int gn = n0 + wn * 32 + jn * 16 + ml;
#pragma unroll
      for (int reg = 0; reg < 4; reg++) {
        int gm = m0 + wm * 32 + im * 16 + q * 4 + reg;
        if (gm >= M) continue;
        float v = acc[im][jn][reg];
        if (EPI == 0) {
          ((unsigned short*)Cout)[(size_t)gm * ldc + gn] = f2h(v);
        } else if (EPI == 1) {
          v += bias[gn];
          v = v / (1.f + __expf(-v));
          ((unsigned short*)Cout)[(size_t)gm * ldc + gn] = f2h(v);
        } else {
          v += (gn < D) ? bias[gn] : 0.f;
          ((float*)Cout)[(size_t)gm * ldc + gn] = v;
        }
      }
    }
  }
}

template <int EPI>
__global__ __launch_bounds__(NTHR) void gemm_kernel(
    const unsigned short* __restrict__ A, const unsigned short* __restrict__ B,
    const float* __restrict__ bias, void* __restrict__ Cout,
    int M, int ncl2, int K, int lda, int ldb, int ldc) {
  __shared__ unsigned short As[64 * 64];
  __shared__ unsigned short Bs[64 * 64];
  gemm_tile<EPI>(A, B, bias, Cout, M, ncl2, K, lda, ldb, ldc, blockIdx.x, As, Bs);
}

// ---------------------------------------------------------------------------
// gather+bracket fused: per block 8 nodes. Half-wave per node gathers the
// projected rows (Sg = sum_e S2[src]) into LDS; bracket consumes from LDS.
// ---------------------------------------------------------------------------
__global__ __launch_bounds__(NTHR) void gather_bracket(
    const unsigned short* __restrict__ S2H, const unsigned short* __restrict__ FH,
    const int* __restrict__ deg, const int* __restrict__ esrc,
    const int* __restrict__ ovfc, const int2* __restrict__ ovf,
    const int* __restrict__ rsK, const int2* __restrict__ trip,
    unsigned short* __restrict__ agg) {
  __shared__ unsigned sSg[8][DP / 2];  // per-node gathered row (half2 col-pairs)
  __shared__ unsigned sS2[4][DP];      // node-pair packed (lo=n0, hi=n1)
  __shared__ unsigned sF2[4][DP];
  const int tid = threadIdx.x;
  const int lane = tid & 63;
  const int half = lane >> 5;
  const int c = lane & 31;
  const int node8 = tid >> 5;
  const int n = blockIdx.x * 8 + node8;

  // ---- gather into sSg ----
  {
    const int dg = deg[n];
    const int dc = (dg < CAP) ? dg : CAP;
    int eid = (c < dc) ? esrc[n * CAP + c] : 0;

    __half2 a0 = __floats2half2_rn(0.f, 0.f), a1 = a0, a2 = a0, a3 = a0;
    __half2 b0 = a0, b1 = a0, b2 = a0, b3 = a0;
    const unsigned short* Sc = S2H + (size_t)c * 8;
    int j = 0;
    for (; j + 2 <= dc; j += 2) {
      int s0 = __shfl(eid, half * 32 + j);
      int s1 = __shfl(eid, half * 32 + j + 1);
      uint4 u0 = *(const uint4*)(Sc + (size_t)s0 * DP);
      uint4 u1 = *(const uint4*)(Sc + (size_t)s1 * DP);
      a0 = __hadd2(a0, __builtin_bit_cast(__half2, u0.x));
      a1 = __hadd2(a1, __builtin_bit_cast(__half2, u0.y));
      a2 = __hadd2(a2, __builtin_bit_cast(__half2, u0.z));
      a3 = __hadd2(a3, __builtin_bit_cast(__half2, u0.w));
      b0 = __hadd2(b0, __builtin_bit_cast(__half2, u1.x));
      b1 = __hadd2(b1, __builtin_bit_cast(__half2, u1.y));
      b2 = __hadd2(b2, __builtin_bit_cast(__half2, u1.z));
      b3 = __hadd2(b3, __builtin_bit_cast(__half2, u1.w));
    }
    if (j < dc) {
      int s = __shfl(eid, half * 32 + j);
      uint4 u0 = *(const uint4*)(Sc + (size_t)s * DP);
      a0 = __hadd2(a0, __builtin_bit_cast(__half2, u0.x));
      a1 = __hadd2(a1, __builtin_bit_cast(__half2, u0.y));
      a2 = __hadd2(a2, __builtin_bit_cast(__half2, u0.z));
      a3 = __hadd2(a3, __builtin_bit_cast(__half2, u0.w));
    }
    if (dg > CAP) {  // correctness path; empty for Poisson(10) inputs
      int novf = *ovfc;
      for (int o = 0; o < novf; o++) {
        int2 e = ovf[o];
        if (e.x == n) {
          uint4 u0 = *(const uint4*)(Sc + (size_t)e.y * DP);
          a0 = __hadd2(a0, __builtin_bit_cast(__half2, u0.x));
          a1 = __hadd2(a1, __builtin_bit_cast(__half2, u0.y));
          a2 = __hadd2(a2, __builtin_bit_cast(__half2, u0.z));
          a3 = __hadd2(a3, __builtin_bit_cast(__half2, u0.w));
        }
      }
    }
    unsigned* d = &sSg[node8][c * 4];
    d[0] = __builtin_bit_cast(unsigned, __hadd2(a0, b0));
    d[1] = __builtin_bit_cast(unsigned, __hadd2(a1, b1));
    d[2] = __builtin_bit_cast(unsigned, __hadd2(a2, b2));
    d[3] = __builtin_bit_cast(unsigned, __hadd2(a3, b3));
  }
  __syncthreads();

  // ---- repack to node-pairs + stage featH pairs ----
  const int wv = tid >> 6;
  const int n0 = blockIdx.x * 8 + wv * 2;
  const int n1 = n0 + 1;
  {
#pragma unroll
    for (int j = 0; j < 4; j++) {
      int k = lane * 4 + j;
      unsigned w0 = sSg[wv * 2][lane * 2 + (j >> 1)];
      unsigned w1 = sSg[wv * 2 + 1][lane * 2 + (j >> 1)];
      unsigned h0 = (j & 1) ? (w0 >> 16) : (w0 & 0xFFFF);
      unsigned h1 = (j & 1) ? (w1 >> 16) : (w1 & 0xFFFF);
      sS2[wv][k] = h0 | (h1 << 16);
    }
    ushort4 u0 = *(const ushort4*)(FH + (size_t)n0 * DP + lane * 4);
    ushort4 u1 = *(const ushort4*)(FH + (size_t)n1 * DP + lane * 4);
    unsigned* d = &sF2[wv][lane * 4];
    d[0] = (unsigned)u0.x | ((unsigned)u1.x << 16);
    d[1] = (unsigned)u0.y | ((unsigned)u1.y << 16);
    d[2] = (unsigned)u0.z | ((unsigned)u1.z << 16);
    d[3] = (unsigned)u0.w | ((unsigned)u1.w << 16);
  }
  __syncthreads();

  // ---- bracket ----
  const unsigned* S2 = sS2[wv];
  const unsigned* F2 = sF2[wv];
#pragma unroll
  for (int kk = 0; kk < 4; kk++) {
    const int k = lane + kk * 64;
    float a0 = 0.f, a1 = 0.f, b0 = 0.f, b1 = 0.f;
    if (k < D) {
      const int tb = rsK[k], te = rsK[k + 1];
      int t = tb;
      for (; t + 2 <= te; t += 2) {
        int2 t0 = trip[t], t1 = trip[t + 1];
        __half2 p0 = __hmul2(__builtin_bit_cast(__half2, S2[t0.x & 0xFFFF]),
                             __builtin_bit_cast(__half2, F2[t0.x >> 16]));
        __half2 p1 = __hmul2(__builtin_bit_cast(__half2, S2[t1.x & 0xFFFF]),
                             __builtin_bit_cast(__half2, F2[t1.x >> 16]));
        float2 q0 = __half22float2(p0);
        float2 q1 = __half22float2(p1);
        const float c0 = __int_as_float(t0.y), c1 = __int_as_float(t1.y);
        a0 += c0 * q0.x; a1 += c0 * q0.y;
        b0 += c1 * q1.x; b1 += c1 * q1.y;
      }
      if (t < te) {
        int2 t0 = trip[t];
        __half2 p0 = __hmul2(__builtin_bit_cast(__half2, S2[t0.x & 0xFFFF]),
                             __builtin_bit_cast(__half2, F2[t0.x >> 16]));
        float2 q0 = __half22float2(p0);
        const float c0 = __int_as_float(t0.y);
        a0 += c0 * q0.x; a1 += c0 * q0.y;
      }
    }
    agg[(size_t)n0 * DP + k] = f2h(a0 + b0);  // k>=D -> 0 pad
    agg[(size_t)n1 * DP + k] = f2h(a1 + b1);
  }
}

// ---------------------------------------------------------------------------
// Residual + LayerNorm, wave-per-node
// ---------------------------------------------------------------------------
__global__ __launch_bounds__(NTHR) void ln_kernel(
    const float* __restrict__ x0, const float* __restrict__ h2,
    const float* __restrict__ gamma, const float* __restrict__ beta,
    float* __restrict__ out) {
  const int tid = threadIdx.x;
  const int wv = tid >> 6;
  const int lane = tid & 63;
  const int n = blockIdx.x * 4 + wv;

  float4 x = make_float4(0.f, 0.f, 0.f, 0.f);
  if (lane < 62) {
    float4 f = *(const float4*)(x0 + (size_t)n * D + lane * 4);
    float4 h = *(const float4*)(h2 + (size_t)n * DP + lane * 4);
    x = make_float4(f.x + h.x, f.y + h.y, f.z + h.z, f.w + h.w);
  }
  float s = x.x + x.y + x.z + x.w;
#pragma unroll
  for (int o = 32; o > 0; o >>= 1) s += __shfl_xor(s, o);
  const float mu = s * (1.f / (float)D);
  float4 xc = make_float4(x.x - mu, x.y - mu, x.z - mu, x.w - mu);
  float v = 0.f;
  if (lane < 62) v = xc.x * xc.x + xc.y * xc.y + xc.z * xc.z + xc.w * xc.w;
#pragma unroll
  for (int o = 32; o > 0; o >>= 1) v += __shfl_xor(v, o);
  const float rstd = rsqrtf(v * (1.f / (float)D) + LN_EPS);
  if (lane < 62) {
    float4 g = *(const float4*)(gamma + lane * 4);
    float4 b = *(const float4*)(beta + lane * 4);
    float4 o;
    o.x = xc.x * rstd * g.x + b.x;
    o.y = xc.y * rstd * g.y + b.y;
    o.z = xc.z * rstd * g.z + b.z;
    o.w = xc.w * rstd * g.w + b.w;
    *(float4*)(out + (size_t)n * D + lane * 4) = o;
  }
}

// ---------------------------------------------------------------------------
extern "C" void kernel_launch(void* const* d_in, const int* in_sizes, int n_in,
                              void* d_out, int out_size, void* d_ws, size_t ws_size,
                              hipStream_t stream) {
  const float* features = (const float*)d_in[0];
  const int*   ei       = (const int*)d_in[1];
  const float* W_msg    = (const float*)d_in[2];
  const float* W1       = (const float*)d_in[3];
  const float* b1       = (const float*)d_in[4];
  const float* W2       = (const float*)d_in[5];
  const float* b2       = (const float*)d_in[6];
  const float* gamma    = (const float*)d_in[7];
  const float* beta     = (const float*)d_in[8];
  const int*   Iv       = (const int*)d_in[9];
  const int*   Jv       = (const int*)d_in[10];
  const int*   Kv       = (const int*)d_in[11];
  const float* Cv       = (const float*)d_in[12];
  float* out = (float*)d_out;

  char* cur = (char*)d_ws;
  auto alloc = [&](size_t bytes) {
    char* p = cur;
    cur += (bytes + 255) & ~(size_t)255;
    return p;
  };
  const size_t NP = (size_t)N_NODES + PAD_ROWS;
  unsigned short* featH = (unsigned short*)alloc(NP * DP * 2);
  unsigned short* WmH   = (unsigned short*)alloc((size_t)DP * DP * 2);
  unsigned short* W1H   = (unsigned short*)alloc((size_t)HDIM * DP * 2);
  unsigned short* W2H   = (unsigned short*)alloc((size_t)DP * HDIM * 2);
  unsigned short* S2H   = (unsigned short*)alloc(NP * DP * 2);
  unsigned short* aggH  = (unsigned short*)alloc(NP * DP * 2);
  unsigned short* H1H   = (unsigned short*)alloc(NP * HDIM * 2);
  float*          H2    = (float*)alloc((size_t)N_NODES * DP * 4);
  int*  rsK  = (int*)alloc((D + 1) * 4);
  int2* trip = (int2*)alloc(NNZ * 8);
  int*  deg  = (int*)alloc((N_NODES + 64) * 4);  // deg[N] then ovfc
  int*  ovfc = deg + N_NODES;
  int*  esrc = (int*)alloc((size_t)N_NODES * CAP * 4);
  int2* ovf  = (int2*)alloc((size_t)N_EDGES * 8);

  dim3 blk(NTHR);

  // 0) zero deg + overflow counter
  hipMemsetAsync(deg, 0, (size_t)(N_NODES + 1) * 4, stream);
  // 1) prep: casts + triple CSR + slot-place
  prep_kernel<<<U_TOTAL, blk, 0, stream>>>(
      features, W_msg, W1, W2, ei, featH, WmH, W1H, W2H,
      Iv, Jv, Kv, Cv, rsK, trip, deg, ovfc, esrc, ovf);
  // 2) S2 = featH @ Wm^T (projection before gather; bilinearity hoist)
  gemm_kernel<0><<<157 * 4, blk, 0, stream>>>(
      featH, WmH, nullptr, S2H, N_NODES, 2, DP, DP, DP, DP);
  // 3) agg = bracket(sum_e S2[src], featH)  (gather fused, Sg in LDS)
  gather_bracket<<<N_NODES / 8, blk, 0, stream>>>(
      S2H, featH, deg, esrc, ovfc, ovf, rsK, trip, aggH);
  // 4) H1 = silu(agg @ W1^T + b1)
  gemm_kernel<1><<<157 * 8, blk, 0, stream>>>(
      aggH, W1H, b1, H1H, N_NODES, 3, DP, DP, DP, HDIM);
  // 5) H2 = H1 @ W2^T + b2 (f32)
  gemm_kernel<2><<<157 * 4, blk, 0, stream>>>(
      H1H, W2H, b2, H2, N_NODES, 2, HDIM, HDIM, HDIM, DP);
  // 6) out = LN(features + H2)
  ln_kernel<<<N_NODES / 4, blk, 0, stream>>>(features, H2, gamma, beta, out);
}